// Round 1
// baseline (1054.364 us; speedup 1.0000x reference)
//
#include <hip/hip_runtime.h>
#include <math.h>

#define NL 28
#define NB 3
#define NH 16
#define NS 1024
#define ND 128
#define VOCAB 151936
#define HIST 64

#define CHUNKS 16
#define CHUNK_LEN (VOCAB / CHUNKS)   // 9496

// d_out flat fp32 layout (element offsets)
#define OFF_TOK  176160768   // tok_col (3)
#define OFF_SAVE 176160771   // save_id_out (3*65)
#define OFF_RP   176160966   // rp (3*151936)
#define OFF_PROB 176616774   // top_beam_prob (3)
#define OFF_MAX  176616777   // max_logits_idx (1)

// workspace word layout:
// partial (b,c): base=(b*CHUNKS+c)*8 -> [0]=m [1]=l [2..4]=v [5..7]=idx
// wsi[384..386] = beam_index, wsi[388..390] = tokens
#define WS_BEAM 384
#define WS_TOK  388

__device__ __forceinline__ void ins3(float x, int ix, float v[3], int iv[3]) {
    if (x > v[0] || (x == v[0] && ix < iv[0])) {
        v[2] = v[1]; iv[2] = iv[1];
        v[1] = v[0]; iv[1] = iv[0];
        v[0] = x;    iv[0] = ix;
    } else if (x > v[1] || (x == v[1] && ix < iv[1])) {
        v[2] = v[1]; iv[2] = iv[1];
        v[1] = x;    iv[1] = ix;
    } else if (x > v[2] || (x == v[2] && ix < iv[2])) {
        v[2] = x;    iv[2] = ix;
    }
}

// K1: per (batch-row, chunk) partial reduction: online softmax state + top-3
__global__ __launch_bounds__(256) void k1_partial(
    const float* __restrict__ logits, const float* __restrict__ rpen,
    float* __restrict__ wsf, int* __restrict__ wsi) {
    const int b = blockIdx.x / CHUNKS;
    const int c = blockIdx.x % CHUNKS;
    const int base = c * CHUNK_LEN;
    const float* lrow = logits + b * VOCAB;
    const float* prow = rpen + b * VOCAB;

    float m = -INFINITY, l = 0.f;
    float v[3] = {-INFINITY, -INFINITY, -INFINITY};
    int iv[3] = {-1, -1, -1};

    for (int j = threadIdx.x; j < CHUNK_LEN; j += 256) {
        int idx = base + j;
        float x = lrow[idx] * prow[idx];
        if (x > m) { l = l * expf(m - x) + 1.f; m = x; }
        else       { l += expf(x - m); }
        ins3(x, idx, v, iv);
    }

    // wave-level (64-lane) reduce
    for (int off = 32; off > 0; off >>= 1) {
        float om = __shfl_down(m, off, 64);
        float ol = __shfl_down(l, off, 64);
        float ov[3]; int oi[3];
#pragma unroll
        for (int k = 0; k < 3; ++k) {
            ov[k] = __shfl_down(v[k], off, 64);
            oi[k] = __shfl_down(iv[k], off, 64);
        }
        float M = fmaxf(m, om);
        l = l * expf(m - M) + ol * expf(om - M);
        m = M;
#pragma unroll
        for (int k = 0; k < 3; ++k) ins3(ov[k], oi[k], v, iv);
    }

    __shared__ float sm[4], sl[4], sv[4][3];
    __shared__ int si[4][3];
    const int lane = threadIdx.x & 63;
    const int wid = threadIdx.x >> 6;
    if (lane == 0) {
        sm[wid] = m; sl[wid] = l;
#pragma unroll
        for (int k = 0; k < 3; ++k) { sv[wid][k] = v[k]; si[wid][k] = iv[k]; }
    }
    __syncthreads();
    if (threadIdx.x == 0) {
        for (int w = 1; w < 4; ++w) {
            float M = fmaxf(m, sm[w]);
            l = l * expf(m - M) + sl[w] * expf(sm[w] - M);
            m = M;
#pragma unroll
            for (int k = 0; k < 3; ++k) ins3(sv[w][k], si[w][k], v, iv);
        }
        const int pbase = (b * CHUNKS + c) * 8;
        wsf[pbase + 0] = m;
        wsf[pbase + 1] = l;
#pragma unroll
        for (int k = 0; k < 3; ++k) {
            wsf[pbase + 2 + k] = v[k];
            wsi[pbase + 5 + k] = iv[k];
        }
    }
}

// K2: merge partials -> per-row top3 lp; beam select; write small outputs
__global__ __launch_bounds__(256) void k2_select(
    const float* __restrict__ prev, const int* __restrict__ save_id,
    const float* __restrict__ wsf, int* __restrict__ wsi,
    float* __restrict__ out) {
    __shared__ float stopv[9];
    __shared__ int stopi[9];
    __shared__ int sbeam[3], stok[3];
    __shared__ float sprob[3];
    const int t = threadIdx.x;

    if (t < NB) {
        float m = -INFINITY, l = 0.f;
        float v[3] = {-INFINITY, -INFINITY, -INFINITY};
        int iv[3] = {-1, -1, -1};
        for (int c = 0; c < CHUNKS; ++c) {
            const int pbase = (t * CHUNKS + c) * 8;
            float pm = wsf[pbase + 0], pl = wsf[pbase + 1];
            float M = fmaxf(m, pm);
            l = l * expf(m - M) + pl * expf(pm - M);
            m = M;
#pragma unroll
            for (int k = 0; k < 3; ++k) ins3(wsf[pbase + 2 + k], wsi[pbase + 5 + k], v, iv);
        }
        const float lse = m + logf(l);
#pragma unroll
        for (int k = 0; k < 3; ++k) {
            stopv[t * 3 + k] = v[k] - lse;
            stopi[t * 3 + k] = iv[k];
        }
    }
    __syncthreads();
    if (t == 0) {
        float cur[9];
        for (int j = 0; j < 9; ++j) cur[j] = stopv[j] + prev[j / 3];
        bool used[9] = {false, false, false, false, false, false, false, false, false};
        for (int i = 0; i < 3; ++i) {
            int best = 0; float bv = -INFINITY;
            for (int j = 0; j < 9; ++j) {
                if (!used[j] && cur[j] > bv) { bv = cur[j]; best = j; }
            }
            used[best] = true;
            sbeam[i] = best / 3;
            stok[i]  = stopi[best];
            sprob[i] = bv;
        }
        for (int i = 0; i < 3; ++i) {
            wsi[WS_BEAM + i] = sbeam[i];
            wsi[WS_TOK + i]  = stok[i];
        }
    }
    __syncthreads();
    if (t < 3) {
        out[OFF_TOK + t]  = (float)stok[t];
        out[OFF_PROB + t] = sprob[t];
    }
    if (t == 0) out[OFF_MAX] = (float)stok[0];
    if (t < 3 * (HIST + 1)) {
        const int i = t / (HIST + 1);
        const int h = t - i * (HIST + 1);
        out[OFF_SAVE + t] = (h < HIST) ? (float)save_id[sbeam[i] * HIST + h]
                                       : (float)stok[i];
    }
}

// K3: kv gather-copy, float4-vectorized. 704.6 MB in + 704.6 MB out.
__global__ __launch_bounds__(256) void k3_kv(
    const float4* __restrict__ kv, const int* __restrict__ wsi,
    float4* __restrict__ out) {
    __shared__ int sbeam[3];
    if (threadIdx.x < 3) sbeam[threadIdx.x] = wsi[WS_BEAM + threadIdx.x];
    __syncthreads();
    const unsigned PER = (NH * NS * ND) / 4;   // 524288 = 1<<19
    unsigned idx = blockIdx.x * 256u + threadIdx.x;
    unsigned li = idx >> 19;                    // 0..83  (l*3 + i)
    unsigned off = idx & (PER - 1);
    unsigned l = li / 3;
    unsigned i = li - l * 3;
    out[idx] = kv[(l * 3 + sbeam[i]) * PER + off];
}

// K4: rp gather + token penalty
__global__ __launch_bounds__(256) void k4_rp(
    const float* __restrict__ rpen, const float* __restrict__ pen,
    const int* __restrict__ wsi, float* __restrict__ out) {
    int idx = blockIdx.x * 256 + threadIdx.x;
    if (idx >= NB * VOCAB) return;
    int i = idx / VOCAB;
    int v = idx - i * VOCAB;
    float x = rpen[wsi[WS_BEAM + i] * VOCAB + v];
    if (v == wsi[WS_TOK + i]) x *= pen[0];
    out[OFF_RP + idx] = x;
}

extern "C" void kernel_launch(void* const* d_in, const int* in_sizes, int n_in,
                              void* d_out, int out_size, void* d_ws, size_t ws_size,
                              hipStream_t stream) {
    const float* kv      = (const float*)d_in[0];
    const float* logits  = (const float*)d_in[1];
    const int*   save_id = (const int*)d_in[2];
    const float* rpen    = (const float*)d_in[3];
    const float* prev    = (const float*)d_in[4];
    const float* pen     = (const float*)d_in[5];
    float* out = (float*)d_out;
    float* wsf = (float*)d_ws;
    int*   wsi = (int*)d_ws;

    k1_partial<<<NB * CHUNKS, 256, 0, stream>>>(logits, rpen, wsf, wsi);
    k2_select<<<1, 256, 0, stream>>>(prev, save_id, wsf, wsi, out);

    const int kv4 = NL * NB * NH * NS * ND / 4;          // 44,040,192 float4
    k3_kv<<<kv4 / 256, 256, 0, stream>>>((const float4*)kv, wsi, (float4*)out);

    k4_rp<<<(NB * VOCAB + 255) / 256, 256, 0, stream>>>(rpen, pen, wsi, out);
}